// Round 7
// baseline (344.529 us; speedup 1.0000x reference)
//
#include <hip/hip_runtime.h>

#define B_ 8
#define C_ 128
#define W_ 4096
#define D_ 16
// D^-0.5 * log2(e): folded into Wq/bq; exp2 domain (v_exp_f32)
#define SCALE2 0.3606737602222409f

typedef short bf16x8 __attribute__((ext_vector_type(8)));
typedef float f32x4 __attribute__((ext_vector_type(4)));

__device__ __forceinline__ unsigned short f2bf(float f) {
    unsigned int u = __float_as_uint(f);
    u += 0x7fffu + ((u >> 16) & 1u);
    return (unsigned short)(u >> 16);
}
// pack two f32 -> u32 of 2 bf16 (TRUNCATED) in ONE v_perm_b32
__device__ __forceinline__ unsigned int pk2bf(float lo, float hi) {
    return __builtin_amdgcn_perm(__float_as_uint(hi), __float_as_uint(lo), 0x07060302u);
}
__device__ __forceinline__ bf16x8 u4_to_bf8(unsigned int a, unsigned int b,
                                            unsigned int c, unsigned int d) {
    union { uint4 u; bf16x8 v; } t;
    t.u = make_uint4(a, b, c, d);
    return t.v;
}
__device__ __forceinline__ bf16x8 uint4_as_bf8(uint4 u) {
    union { uint4 u; bf16x8 v; } t;
    t.u = u;
    return t.v;
}
// exp2 all 8 score values of an adjacent (A,B) j-tile pair -> K=32 B-fragment
__device__ __forceinline__ bf16x8 exp2pack(f32x4 a, f32x4 b) {
    return u4_to_bf8(
        pk2bf(__builtin_amdgcn_exp2f(a[0]), __builtin_amdgcn_exp2f(a[1])),
        pk2bf(__builtin_amdgcn_exp2f(a[2]), __builtin_amdgcn_exp2f(a[3])),
        pk2bf(__builtin_amdgcn_exp2f(b[0]), __builtin_amdgcn_exp2f(b[1])),
        pk2bf(__builtin_amdgcn_exp2f(b[2]), __builtin_amdgcn_exp2f(b[3])));
}
// LDS chunk swizzle for proj staging: <=2-way banks both directions
__device__ __forceinline__ int xswz(int j, int c8) {
    return c8 ^ (j & 7) ^ ((j >> 3) & 7);
}

// ---------------- prep: Wv -> bf16; [Wq*SCALE2 ; Wk] -> bf16 ----------------
__global__ __launch_bounds__(256) void prep(
    const float* __restrict__ Wq, const float* __restrict__ Wk, const float* __restrict__ Wv,
    unsigned short* __restrict__ Wvbf, unsigned short* __restrict__ Wqkbf)
{
    int g = blockIdx.x * 256 + threadIdx.x;
    const float* src; unsigned short* dst; float sc = 1.0f;
    if (g < 4096)      { src = Wv + g * 4;            dst = Wvbf + g * 4; }
    else if (g < 4608) { int t = g - 4096; src = Wq + t * 4; dst = Wqkbf + t * 4; sc = SCALE2; }
    else               { int t = g - 4608; src = Wk + t * 4; dst = Wqkbf + 2048 + t * 4; }
    float4 v = *(const float4*)src;
    unsigned short h[4] = {f2bf(v.x * sc), f2bf(v.y * sc), f2bf(v.z * sc), f2bf(v.w * sc)};
    *(ushort4*)dst = *(ushort4*)h;
}

// ---------------- proj: q,k,v in one pass (MFMA), j-strip 32, grid 1024 ----------------
// qws/kws: [b][plane 0..3][pos][8] bf16. plane2 of k = {1.0,0...}; plane2 of q
// zeroed here, slot0 later filled with -log2(l) by finl. plane3 = 0.
// vws: PAIRED layout [b][jpair][c][q4][8] bf16, slot i<4: jtA j=q4*4+i, i>=4: jtB
__global__ __launch_bounds__(256) void proj(
    const float* __restrict__ x, const unsigned short* __restrict__ Wvbf,
    const unsigned short* __restrict__ Wqkbf,
    const float* __restrict__ bqp, const float* __restrict__ bkp, const float* __restrict__ bvp,
    unsigned short* __restrict__ qws, unsigned short* __restrict__ kws,
    unsigned short* __restrict__ vws)
{
    __shared__ unsigned short xbf[32 * 128];    // [j][c] swizzled chunks, 8KB
    __shared__ unsigned short outs[128 * 40];   // v-store bounce, 10.2KB

    int b  = blockIdx.x & 7;
    int j0 = (blockIdx.x >> 3) * 32;
    int tid = threadIdx.x;
    int wid = tid >> 6, lane = tid & 63, n = lane & 15, q4 = lane >> 4;

    // stage x tile [128c][32j] -> bf16 LDS [j][c] swizzled
#pragma unroll
    for (int i = 0; i < 4; i++) {
        int idx = tid + 256 * i;                // 1024 float4 slots
        int c = idx >> 3, jc = (idx & 7) * 4;
        float4 t = *(const float4*)(x + (size_t)(b * C_ + c) * W_ + j0 + jc);
        float tv[4] = {t.x, t.y, t.z, t.w};
#pragma unroll
        for (int cc = 0; cc < 4; cc++) {
            int j = jc + cc;
            xbf[j * 128 + xswz(j, c >> 3) * 8 + (c & 7)] = f2bf(tv[cc]);
        }
    }
    __syncthreads();

    const f32x4 zero = {0.f, 0.f, 0.f, 0.f};
    f32x4 accv[2][2]; f32x4 accqk = zero;
#pragma unroll
    for (int os = 0; os < 2; os++)
#pragma unroll
        for (int js = 0; js < 2; js++) accv[os][js] = zero;

    int isK = wid >> 1;          // waves 0,1: q; waves 2,3: k
    int jsm = wid & 1;           // which j-tile this wave's q/k MFMA covers

#pragma unroll
    for (int kk = 0; kk < 128; kk += 32) {
        bf16x8 av[2], aqkf, bx[2];
#pragma unroll
        for (int os = 0; os < 2; os++)
            av[os] = *(const bf16x8*)(Wvbf + (wid * 32 + os * 16 + n) * 128 + kk + q4 * 8);
        aqkf = *(const bf16x8*)(Wqkbf + (isK * 16 + n) * 128 + kk + q4 * 8);
#pragma unroll
        for (int js = 0; js < 2; js++) {
            int j = js * 16 + n;
            bx[js] = *(const bf16x8*)&xbf[j * 128 + xswz(j, (kk >> 3) + q4) * 8];
        }
#pragma unroll
        for (int os = 0; os < 2; os++)
#pragma unroll
            for (int js = 0; js < 2; js++)
                accv[os][js] = __builtin_amdgcn_mfma_f32_16x16x32_bf16(av[os], bx[js], accv[os][js], 0, 0, 0);
        accqk = __builtin_amdgcn_mfma_f32_16x16x32_bf16(aqkf, bx[jsm], accqk, 0, 0, 0);
    }

    // q/k epilogue: wave (isK,jsm) writes 16 positions
    {
        int pos = j0 + jsm * 16 + n;
        const float* bias = isK ? bkp : bqp;
        float bsc = isK ? 1.0f : SCALE2;
        float v0 = accqk[0] + bias[q4 * 4 + 0] * bsc;
        float v1 = accqk[1] + bias[q4 * 4 + 1] * bsc;
        float v2 = accqk[2] + bias[q4 * 4 + 2] * bsc;
        float v3 = accqk[3] + bias[q4 * 4 + 3] * bsc;
        unsigned short* basep = isK ? kws : qws;
        size_t base = ((size_t)(b * 4 + (q4 >> 1)) * W_ + pos) * 8 + (q4 & 1) * 4;
        *(uint2*)(basep + base) = make_uint2((unsigned)f2bf(v0) | ((unsigned)f2bf(v1) << 16),
                                             (unsigned)f2bf(v2) | ((unsigned)f2bf(v3) << 16));
    }
    // planes 2,3: zero, except k plane2 dim16 = 1.0 (bf16 0x3f80)
    if (tid < 128) {
        int which = tid >> 6;                  // 0: q, 1: k
        int plane = 2 + ((tid >> 5) & 1);
        int pos = j0 + (tid & 31);
        unsigned short* basep = which ? kws : qws;
        uint4 z = make_uint4(0, 0, 0, 0);
        if (which == 1 && plane == 2) z.x = 0x3f80u;
        *(uint4*)(basep + ((size_t)(b * 4 + plane) * W_ + pos) * 8) = z;
    }

    // v epilogue -> LDS bounce -> paired layout
    float bvv[2][4];
#pragma unroll
    for (int os = 0; os < 2; os++)
#pragma unroll
        for (int r = 0; r < 4; r++) bvv[os][r] = bvp[wid * 32 + os * 16 + q4 * 4 + r];
#pragma unroll
    for (int os = 0; os < 2; os++)
#pragma unroll
        for (int js = 0; js < 2; js++)
#pragma unroll
            for (int r = 0; r < 4; r++) {
                int c = wid * 32 + os * 16 + q4 * 4 + r;
                int j = js * 16 + n;
                outs[c * 40 + j] = f2bf(accv[os][js][r] + bvv[os][r]);
            }
    __syncthreads();
    // this block covers exactly one jpair = j0/32; write [c][q4][jtA4|jtB4]
    {
        int jp = j0 >> 5;
#pragma unroll
        for (int rep = 0; rep < 2; rep++) {
            int idx = tid + 256 * rep;          // 0..511
            int c = idx >> 2, q4g = idx & 3;
            uint2 lo = *(const uint2*)&outs[c * 40 + q4g * 4];         // jtA
            uint2 hi = *(const uint2*)&outs[c * 40 + 16 + q4g * 4];    // jtB
            *(uint4*)(vws + ((((size_t)(b * 128 + jp) * 128 + c) * 4) + q4g) * 8) =
                make_uint4(lo.x, lo.y, hi.x, hi.y);
        }
    }
}

// ---------------- row_stats: partial l-sums, w split 4 ways, pipelined ----------------
__global__ __launch_bounds__(256) void row_stats(
    const unsigned short* __restrict__ qws, const unsigned short* __restrict__ kws,
    float* __restrict__ rlp)
{
    int blk = blockIdx.x;
    int b = blk & 7;
    int j0 = ((blk >> 3) & 63) * 64;
    int wsp = blk >> 9;                 // 0..3
    int t0 = wsp * 16;                  // 16 key tiles of 64
    int tid = threadIdx.x;
    int wid = tid >> 6, lane = tid & 63, n = lane & 15, q4 = lane >> 4;

    const bf16x8* qbase = (const bf16x8*)qws + (size_t)(b * 4 + q4) * W_;
    const bf16x8* kbase = (const bf16x8*)kws + (size_t)(b * 4 + q4) * W_;
    bf16x8 aq = qbase[j0 + wid * 16 + n];
    const f32x4 zero = {0.f, 0.f, 0.f, 0.f};

    float lt[4] = {0.f, 0.f, 0.f, 0.f};
    bf16x8 k0[4], k1[4];
#pragma unroll
    for (int ws = 0; ws < 4; ws++) {
        k0[ws] = kbase[(t0 + 0) * 64 + ws * 16 + n];
        k1[ws] = kbase[(t0 + 1) * 64 + ws * 16 + n];
    }

#pragma unroll 2
    for (int t = 0; t < 8; t++) {
        f32x4 sa[4], sb[4];
#pragma unroll
        for (int ws = 0; ws < 4; ws++)
            sa[ws] = __builtin_amdgcn_mfma_f32_16x16x32_bf16(aq, k0[ws], zero, 0, 0, 0);
#pragma unroll
        for (int ws = 0; ws < 4; ws++)
            sb[ws] = __builtin_amdgcn_mfma_f32_16x16x32_bf16(aq, k1[ws], zero, 0, 0, 0);
        int ta = t0 + ((2 * t + 2) & 15), tb = t0 + ((2 * t + 3) & 15);
#pragma unroll
        for (int ws = 0; ws < 4; ws++) {
            k0[ws] = kbase[ta * 64 + ws * 16 + n];
            k1[ws] = kbase[tb * 64 + ws * 16 + n];
        }
#pragma unroll
        for (int ws = 0; ws < 4; ws++)
#pragma unroll
            for (int r = 0; r < 4; r++) {
                lt[r] += __builtin_amdgcn_exp2f(sa[ws][r]);
                lt[r] += __builtin_amdgcn_exp2f(sb[ws][r]);
            }
    }
#pragma unroll
    for (int mask = 1; mask < 16; mask <<= 1)
#pragma unroll
        for (int r = 0; r < 4; r++) lt[r] += __shfl_xor(lt[r], mask, 64);
    if (n == 0) {
        f32x4 l4 = {lt[0], lt[1], lt[2], lt[3]};
        *(f32x4*)(rlp + (size_t)wsp * 32768 + (size_t)b * W_ + j0 + wid * 16 + q4 * 4) = l4;
    }
}

// ---------------- finl: l = sum of 4 partials; q plane2 slot0 <- -log2(l) ----------------
__global__ __launch_bounds__(256) void finl(const float* __restrict__ rlp,
                                            unsigned short* __restrict__ qws)
{
    int g = blockIdx.x * 256 + threadIdx.x;   // 32768 = B*W
    int b = g >> 12, j = g & (W_ - 1);
    float l = rlp[g] + rlp[32768 + g] + rlp[65536 + g] + rlp[98304 + g];
    qws[((size_t)(b * 4 + 2) * W_ + j) * 8] = f2bf(-__builtin_amdgcn_logf(l));
}

// ---------------- attn_out: barrier-free K-loop, register-lean pipeline ----------------
// Wave owns ADJACENT j-tiles jtA=it*8+wid*2, jtB=jtA+1 (jpair=it*4+wid).
// S C-layout == PV B-fragment; PV A-fragment = ONE dwordx4 from paired vws.
__global__ __launch_bounds__(256, 2) void attn_out(
    const float* __restrict__ x, const unsigned short* __restrict__ qws,
    const unsigned short* __restrict__ kws, const unsigned short* __restrict__ vws,
    float* __restrict__ out)
{
    __shared__ float red[2][128 * 68];   // 69.6 KB: reduction + store bounce

    int b  = blockIdx.x & 7;
    int w0 = (blockIdx.x >> 3) * 64;
    int tid = threadIdx.x;
    int wid = tid >> 6, lane = tid & 63, n = lane & 15, q4 = lane >> 4;

    const bf16x8* qbase = (const bf16x8*)qws + (size_t)(b * 4 + q4) * W_;
    const bf16x8* kbase = (const bf16x8*)kws + (size_t)(b * 4 + q4) * W_;
    const unsigned short* vtb = vws + (size_t)b * 128 * 128 * 32;

    bf16x8 bk[4];
#pragma unroll
    for (int ws = 0; ws < 4; ws++) bk[ws] = kbase[w0 + ws * 16 + n];

    const f32x4 zero = {0.f, 0.f, 0.f, 0.f};
    f32x4 acc[8][4];   // [mt(c)][nt(w)]
#pragma unroll
    for (int mt = 0; mt < 8; mt++)
#pragma unroll
        for (int nt = 0; nt < 4; nt++) acc[mt][nt] = zero;

    // ---- prologue: vf(0), S(0), aq(1), bfrag(0) ----
    bf16x8 aqA = qbase[wid * 32 + n];
    bf16x8 aqB = qbase[wid * 32 + 16 + n];
    uint4 vf[8];
#pragma unroll
    for (int mt = 0; mt < 8; mt++) {
        int c = mt * 16 + n;
        vf[mt] = *(const uint4*)(vtb + (((size_t)(wid * 128 + c) * 4) + q4) * 8);
    }
    f32x4 sA[4], sB[4];
#pragma unroll
    for (int ws = 0; ws < 4; ws++) {
        sA[ws] = __builtin_amdgcn_mfma_f32_16x16x32_bf16(aqA, bk[ws], zero, 0, 0, 0);
        sB[ws] = __builtin_amdgcn_mfma_f32_16x16x32_bf16(aqB, bk[ws], zero, 0, 0, 0);
    }
    aqA = qbase[128 + wid * 32 + n];
    aqB = qbase[128 + wid * 32 + 16 + n];
    bf16x8 bfrag[4];
#pragma unroll
    for (int ws = 0; ws < 4; ws++) bfrag[ws] = exp2pack(sA[ws], sB[ws]);

    for (int it = 0; it < 32; it++) {
        // (1) S-MFMAs for it+1
#pragma unroll
        for (int ws = 0; ws < 4; ws++) {
            sA[ws] = __builtin_amdgcn_mfma_f32_16x16x32_bf16(aqA, bk[ws], zero, 0, 0, 0);
            sB[ws] = __builtin_amdgcn_mfma_f32_16x16x32_bf16(aqB, bk[ws], zero, 0, 0, 0);
        }
        // (2) q loads for it+2
        int itn2 = (it + 2) & 31;
        aqA = qbase[itn2 * 128 + wid * 32 + n];
        aqB = qbase[itn2 * 128 + wid * 32 + 16 + n];
        // (3) PV for it (consumes vf + bfrag of it)
#pragma unroll
        for (int mt = 0; mt < 8; mt++) {
            bf16x8 af = uint4_as_bf8(vf[mt]);
#pragma unroll
            for (int nt = 0; nt < 4; nt++)
                acc[mt][nt] = __builtin_amdgcn_mfma_f32_16x16x32_bf16(af, bfrag[nt], acc[mt][nt], 0, 0, 0);
        }
        // (4) vf loads for it+1 (regs free after PV; ~full stage ahead of use)
        int itn = (it + 1) & 31;
        int jpn = itn * 4 + wid;
#pragma unroll
        for (int mt = 0; mt < 8; mt++) {
            int c = mt * 16 + n;
            vf[mt] = *(const uint4*)(vtb + (((size_t)(jpn * 128 + c) * 4) + q4) * 8);
        }
        // (5) bfrag for it+1
#pragma unroll
        for (int ws = 0; ws < 4; ws++) bfrag[ws] = exp2pack(sA[ws], sB[ws]);
    }

    // ---- cross-wave reduction (4 waves) ----
    if (wid >= 2) {
        float* buf = red[wid - 2];
#pragma unroll
        for (int mt = 0; mt < 8; mt++)
#pragma unroll
            for (int nt = 0; nt < 4; nt++)
#pragma unroll
                for (int r = 0; r < 4; r++)
                    buf[(mt * 16 + q4 * 4 + r) * 68 + nt * 16 + n] = acc[mt][nt][r];
    }
    __syncthreads();
    if (wid < 2) {
        const float* buf = red[wid];
#pragma unroll
        for (int mt = 0; mt < 8; mt++)
#pragma unroll
            for (int nt = 0; nt < 4; nt++)
#pragma unroll
                for (int r = 0; r < 4; r++)
                    acc[mt][nt][r] += buf[(mt * 16 + q4 * 4 + r) * 68 + nt * 16 + n];
    }
    __syncthreads();
    if (wid == 1) {
        float* buf = red[0];
#pragma unroll
        for (int mt = 0; mt < 8; mt++)
#pragma unroll
            for (int nt = 0; nt < 4; nt++)
#pragma unroll
                for (int r = 0; r < 4; r++)
                    buf[(mt * 16 + q4 * 4 + r) * 68 + nt * 16 + n] = acc[mt][nt][r];
    }
    __syncthreads();
    if (wid == 0) {
        float* buf = red[0];
#pragma unroll
        for (int mt = 0; mt < 8; mt++)
#pragma unroll
            for (int nt = 0; nt < 4; nt++)
#pragma unroll
                for (int r = 0; r < 4; r++) {
                    int idx = (mt * 16 + q4 * 4 + r) * 68 + nt * 16 + n;
                    buf[idx] = acc[mt][nt][r] + buf[idx];
                }
    }
    __syncthreads();
    // coalesced store: out = red[0] + x
    {
#pragma unroll
        for (int u = 0; u < 8; u++) {
            int k = tid + 256 * u;          // 2048 float4 slots
            int c = k >> 4, wseg = (k & 15) * 4;
            size_t gidx = (size_t)(b * C_ + c) * W_ + w0 + wseg;
            float4 xv = *(const float4*)(x + gidx);
            const float* s = &red[0][c * 68 + wseg];
            float4 o = make_float4(s[0] + xv.x, s[1] + xv.y, s[2] + xv.z, s[3] + xv.w);
            *(float4*)(out + gidx) = o;
        }
    }
}

extern "C" void kernel_launch(void* const* d_in, const int* in_sizes, int n_in,
                              void* d_out, int out_size, void* d_ws, size_t ws_size,
                              hipStream_t stream)
{
    const float* x  = (const float*)d_in[0];
    const float* Wq = (const float*)d_in[1];
    const float* bq = (const float*)d_in[2];
    const float* Wk = (const float*)d_in[3];
    const float* bk = (const float*)d_in[4];
    const float* Wv = (const float*)d_in[5];
    const float* bv = (const float*)d_in[6];
    float* out = (float*)d_out;

    unsigned short* qws  = (unsigned short*)d_ws;        // [B][4][W][8] bf16 = 2MB
    unsigned short* kws  = qws + (size_t)1048576;        // [B][4][W][8] bf16 = 2MB
    unsigned short* vws  = kws + (size_t)1048576;        // [B][128][128][4][8] bf16 = 8MB
    unsigned short* Wvbf = vws + (size_t)4194304;        // [128][128]
    unsigned short* Wqkbf = Wvbf + 16384;                // [32][128] (q rows pre-scaled)
    float* rlp = (float*)(Wqkbf + 4096);                 // [4][B][W] partial l-sums

    prep<<<20, 256, 0, stream>>>(Wq, Wk, Wv, Wvbf, Wqkbf);
    proj<<<1024, 256, 0, stream>>>(x, Wvbf, Wqkbf, bq, bk, bv, qws, kws, vws);
    row_stats<<<2048, 256, 0, stream>>>(qws, kws, rlp);
    finl<<<128, 256, 0, stream>>>(rlp, qws);
    attn_out<<<512, 256, 0, stream>>>(x, qws, kws, vws, out);
}

// Round 8
// 162.675 us; speedup vs baseline: 2.1179x; 2.1179x over previous
//
#include <hip/hip_runtime.h>

#define B_ 8
#define C_ 128
#define W_ 4096
#define D_ 16
// D^-0.5 * log2(e): folded into Wq/bq; exp2 domain (v_exp_f32)
#define SCALE2 0.3606737602222409f

typedef short bf16x8 __attribute__((ext_vector_type(8)));
typedef float f32x4 __attribute__((ext_vector_type(4)));

__device__ __forceinline__ unsigned short f2bf(float f) {
    unsigned int u = __float_as_uint(f);
    u += 0x7fffu + ((u >> 16) & 1u);
    return (unsigned short)(u >> 16);
}
// pack two f32 -> u32 of 2 bf16 (TRUNCATED) in ONE v_perm_b32
__device__ __forceinline__ unsigned int pk2bf(float lo, float hi) {
    return __builtin_amdgcn_perm(__float_as_uint(hi), __float_as_uint(lo), 0x07060302u);
}
__device__ __forceinline__ bf16x8 u4_to_bf8(unsigned int a, unsigned int b,
                                            unsigned int c, unsigned int d) {
    union { uint4 u; bf16x8 v; } t;
    t.u = make_uint4(a, b, c, d);
    return t.v;
}
// exp2 all 8 score values of an (A,B) j-tile pair and pack to a K=32 B-fragment
__device__ __forceinline__ bf16x8 exp2pack(f32x4 a, f32x4 b) {
    return u4_to_bf8(
        pk2bf(__builtin_amdgcn_exp2f(a[0]), __builtin_amdgcn_exp2f(a[1])),
        pk2bf(__builtin_amdgcn_exp2f(a[2]), __builtin_amdgcn_exp2f(a[3])),
        pk2bf(__builtin_amdgcn_exp2f(b[0]), __builtin_amdgcn_exp2f(b[1])),
        pk2bf(__builtin_amdgcn_exp2f(b[2]), __builtin_amdgcn_exp2f(b[3])));
}
// LDS chunk swizzle for proj staging: low-conflict both directions
__device__ __forceinline__ int xswz(int j, int c8) {
    return c8 ^ (j & 7) ^ ((j >> 3) & 7);
}

// ---------------- prep: Wv -> bf16; [Wq*SCALE2 ; Wk] -> bf16 ----------------
__global__ __launch_bounds__(256) void prep(
    const float* __restrict__ Wq, const float* __restrict__ Wk, const float* __restrict__ Wv,
    unsigned short* __restrict__ Wvbf, unsigned short* __restrict__ Wqkbf)
{
    int g = blockIdx.x * 256 + threadIdx.x;
    const float* src; unsigned short* dst; float sc = 1.0f;
    if (g < 4096)      { src = Wv + g * 4;            dst = Wvbf + g * 4; }
    else if (g < 4608) { int t = g - 4096; src = Wq + t * 4; dst = Wqkbf + t * 4; sc = SCALE2; }
    else               { int t = g - 4608; src = Wk + t * 4; dst = Wqkbf + 2048 + t * 4; }
    float4 v = *(const float4*)src;
    unsigned short h[4] = {f2bf(v.x * sc), f2bf(v.y * sc), f2bf(v.z * sc), f2bf(v.w * sc)};
    *(ushort4*)dst = *(ushort4*)h;
}

// ---------------- proj: q,k,v in one pass (MFMA), j-strip 32, grid 1024 ----------------
// qws/kws: [b][plane 0..3][pos][8] bf16. plane2 of k = {1.0,0...}; plane2 of q
// zeroed here, slot0 later filled with -log2(l) by finl. plane3 = 0.
// vws: j-tiled [b][j/16][c][j%16] bf16
__global__ __launch_bounds__(256) void proj(
    const float* __restrict__ x, const unsigned short* __restrict__ Wvbf,
    const unsigned short* __restrict__ Wqkbf,
    const float* __restrict__ bqp, const float* __restrict__ bkp, const float* __restrict__ bvp,
    unsigned short* __restrict__ qws, unsigned short* __restrict__ kws,
    unsigned short* __restrict__ vws)
{
    __shared__ unsigned short xbf[32 * 128];    // [j][c] swizzled chunks, 8KB
    __shared__ unsigned short outs[128 * 40];   // v-store bounce, 10.2KB

    int b  = blockIdx.x & 7;
    int j0 = (blockIdx.x >> 3) * 32;
    int tid = threadIdx.x;
    int wid = tid >> 6, lane = tid & 63, n = lane & 15, q4 = lane >> 4;

    // stage x tile [128c][32j] -> bf16 LDS [j][c] swizzled; c-paired v_perm packs
    {
        unsigned int* xbf32 = (unsigned int*)xbf;
#pragma unroll
        for (int i = 0; i < 8; i++) {
            int p = tid + 256 * i;            // 2048 c-pair slots
            int c2 = p >> 5;                  // c = 2*c2, 2*c2+1
            int j  = p & 31;
            const float* xp = x + (size_t)(b * C_ + 2 * c2) * W_ + j0 + j;
            float lo = xp[0];
            float hi = xp[W_];
            xbf32[j * 64 + xswz(j, c2 >> 2) * 4 + (c2 & 3)] = pk2bf(lo, hi);
        }
    }
    __syncthreads();

    const f32x4 zero = {0.f, 0.f, 0.f, 0.f};
    f32x4 accv[2][2]; f32x4 accqk = zero;
#pragma unroll
    for (int os = 0; os < 2; os++)
#pragma unroll
        for (int js = 0; js < 2; js++) accv[os][js] = zero;

    int isK = wid >> 1;          // waves 0,1: q; waves 2,3: k
    int jsm = wid & 1;           // which j-tile this wave's q/k MFMA covers

#pragma unroll
    for (int kk = 0; kk < 128; kk += 32) {
        bf16x8 av[2], aqkf, bx[2];
#pragma unroll
        for (int os = 0; os < 2; os++)
            av[os] = *(const bf16x8*)(Wvbf + (wid * 32 + os * 16 + n) * 128 + kk + q4 * 8);
        aqkf = *(const bf16x8*)(Wqkbf + (isK * 16 + n) * 128 + kk + q4 * 8);
#pragma unroll
        for (int js = 0; js < 2; js++) {
            int j = js * 16 + n;
            bx[js] = *(const bf16x8*)&xbf[j * 128 + xswz(j, (kk >> 3) + q4) * 8];
        }
#pragma unroll
        for (int os = 0; os < 2; os++)
#pragma unroll
            for (int js = 0; js < 2; js++)
                accv[os][js] = __builtin_amdgcn_mfma_f32_16x16x32_bf16(av[os], bx[js], accv[os][js], 0, 0, 0);
        accqk = __builtin_amdgcn_mfma_f32_16x16x32_bf16(aqkf, bx[jsm], accqk, 0, 0, 0);
    }

    // q/k epilogue: wave (isK,jsm) writes 16 positions
    {
        int pos = j0 + jsm * 16 + n;
        const float* bias = isK ? bkp : bqp;
        float bsc = isK ? 1.0f : SCALE2;
        float v0 = accqk[0] + bias[q4 * 4 + 0] * bsc;
        float v1 = accqk[1] + bias[q4 * 4 + 1] * bsc;
        float v2 = accqk[2] + bias[q4 * 4 + 2] * bsc;
        float v3 = accqk[3] + bias[q4 * 4 + 3] * bsc;
        unsigned short* basep = isK ? kws : qws;
        size_t base = ((size_t)(b * 4 + (q4 >> 1)) * W_ + pos) * 8 + (q4 & 1) * 4;
        *(uint2*)(basep + base) = make_uint2(pk2bf(v0, v1), pk2bf(v2, v3));
    }
    // planes 2,3: zero, except k plane2 dim16 = 1.0 (bf16 0x3f80)
    if (tid < 128) {
        int which = tid >> 6;                  // 0: q, 1: k
        int plane = 2 + ((tid >> 5) & 1);
        int pos = j0 + (tid & 31);
        unsigned short* basep = which ? kws : qws;
        uint4 z = make_uint4(0, 0, 0, 0);
        if (which == 1 && plane == 2) z.x = 0x3f80u;
        *(uint4*)(basep + ((size_t)(b * 4 + plane) * W_ + pos) * 8) = z;
    }

    // v epilogue -> LDS bounce -> j-tiled layout
    float bvv[2][4];
#pragma unroll
    for (int os = 0; os < 2; os++)
#pragma unroll
        for (int r = 0; r < 4; r++) bvv[os][r] = bvp[wid * 32 + os * 16 + q4 * 4 + r];
#pragma unroll
    for (int os = 0; os < 2; os++)
#pragma unroll
        for (int js = 0; js < 2; js++)
#pragma unroll
            for (int r = 0; r < 4; r++) {
                int c = wid * 32 + os * 16 + q4 * 4 + r;
                int j = js * 16 + n;
                outs[c * 40 + j] = f2bf(accv[os][js][r] + bvv[os][r]);
            }
    __syncthreads();
    {
        int jt_l = tid >> 7;          // 0..1
        int c    = tid & 127;
        const uint4* src = (const uint4*)&outs[c * 40 + jt_l * 16];
        unsigned short* dst = vws + ((size_t)((b * 256 + (j0 >> 4) + jt_l) * 128 + c)) * 16;
        *(uint4*)(dst + 0) = src[0];
        *(uint4*)(dst + 8) = src[1];
    }
}

// ---------------- row_stats: partial l-sums, w split 4 ways, pipelined ----------------
__global__ __launch_bounds__(256) void row_stats(
    const unsigned short* __restrict__ qws, const unsigned short* __restrict__ kws,
    float* __restrict__ rlp)
{
    int blk = blockIdx.x;
    int b = blk & 7;
    int j0 = ((blk >> 3) & 63) * 64;
    int wsp = blk >> 9;                 // 0..3
    int t0 = wsp * 16;                  // 16 key tiles of 64
    int tid = threadIdx.x;
    int wid = tid >> 6, lane = tid & 63, n = lane & 15, q4 = lane >> 4;

    const bf16x8* qbase = (const bf16x8*)qws + (size_t)(b * 4 + q4) * W_;
    const bf16x8* kbase = (const bf16x8*)kws + (size_t)(b * 4 + q4) * W_;
    bf16x8 aq = qbase[j0 + wid * 16 + n];
    const f32x4 zero = {0.f, 0.f, 0.f, 0.f};

    float lt[4] = {0.f, 0.f, 0.f, 0.f};
    bf16x8 k0[4], k1[4];
#pragma unroll
    for (int ws = 0; ws < 4; ws++) {
        k0[ws] = kbase[(t0 + 0) * 64 + ws * 16 + n];
        k1[ws] = kbase[(t0 + 1) * 64 + ws * 16 + n];
    }

#pragma unroll 2
    for (int t = 0; t < 8; t++) {
        f32x4 sa[4], sb[4];
#pragma unroll
        for (int ws = 0; ws < 4; ws++)
            sa[ws] = __builtin_amdgcn_mfma_f32_16x16x32_bf16(aq, k0[ws], zero, 0, 0, 0);
#pragma unroll
        for (int ws = 0; ws < 4; ws++)
            sb[ws] = __builtin_amdgcn_mfma_f32_16x16x32_bf16(aq, k1[ws], zero, 0, 0, 0);
        int ta = t0 + ((2 * t + 2) & 15), tb = t0 + ((2 * t + 3) & 15);
#pragma unroll
        for (int ws = 0; ws < 4; ws++) {
            k0[ws] = kbase[ta * 64 + ws * 16 + n];
            k1[ws] = kbase[tb * 64 + ws * 16 + n];
        }
#pragma unroll
        for (int ws = 0; ws < 4; ws++)
#pragma unroll
            for (int r = 0; r < 4; r++) {
                lt[r] += __builtin_amdgcn_exp2f(sa[ws][r]);
                lt[r] += __builtin_amdgcn_exp2f(sb[ws][r]);
            }
    }
#pragma unroll
    for (int mask = 1; mask < 16; mask <<= 1)
#pragma unroll
        for (int r = 0; r < 4; r++) lt[r] += __shfl_xor(lt[r], mask, 64);
    if (n == 0) {
        f32x4 l4 = {lt[0], lt[1], lt[2], lt[3]};
        *(f32x4*)(rlp + (size_t)wsp * 32768 + (size_t)b * W_ + j0 + wid * 16 + q4 * 4) = l4;
    }
}

// ---------------- finl: l = sum of 4 partials; q plane2 slot0 <- -log2(l) ----------------
__global__ __launch_bounds__(256) void finl(const float* __restrict__ rlp,
                                            unsigned short* __restrict__ qws)
{
    int g = blockIdx.x * 256 + threadIdx.x;   // 32768 = B*W
    int b = g >> 12, j = g & (W_ - 1);
    float l = rlp[g] + rlp[32768 + g] + rlp[65536 + g] + rlp[98304 + g];
    qws[((size_t)(b * 4 + 2) * W_ + j) * 8] = f2bf(-__builtin_amdgcn_logf(l));
}

// ---------------- attn_out: R5-proven barrier-free pipelined K-loop ----------------
// Wave owns j-tiles jtA=it*8+wid, jtB=jtA+4; S C-layout == PV B-fragment under the
// k-slot<->j bijection; v A-frags double-buffered uint2 pairs from j-tiled vws.
__global__ __launch_bounds__(256, 2) void attn_out(
    const float* __restrict__ x, const unsigned short* __restrict__ qws,
    const unsigned short* __restrict__ kws, const unsigned short* __restrict__ vws,
    float* __restrict__ out)
{
    __shared__ float red[2][128 * 68];   // 69.6 KB: reduction + store bounce

    int b  = blockIdx.x & 7;
    int w0 = (blockIdx.x >> 3) * 64;
    int tid = threadIdx.x;
    int wid = tid >> 6, lane = tid & 63, n = lane & 15, q4 = lane >> 4;

    const bf16x8* qbase = (const bf16x8*)qws + (size_t)(b * 4 + q4) * W_;
    const bf16x8* kbase = (const bf16x8*)kws + (size_t)(b * 4 + q4) * W_;
    const unsigned short* vtb = vws + (size_t)b * 256 * 128 * 16;

    bf16x8 bk[4];
#pragma unroll
    for (int ws = 0; ws < 4; ws++) bk[ws] = kbase[w0 + ws * 16 + n];

    const f32x4 zero = {0.f, 0.f, 0.f, 0.f};
    f32x4 acc[8][4];   // [mt(c)][nt(w)]
#pragma unroll
    for (int mt = 0; mt < 8; mt++)
#pragma unroll
        for (int nt = 0; nt < 4; nt++) acc[mt][nt] = zero;

    // ---- pipeline prologue (it = 0) ----
    bf16x8 aqA = qbase[wid * 16 + n];
    bf16x8 aqB = qbase[64 + wid * 16 + n];
    uint2 vfA[8], vfB[8];
#pragma unroll
    for (int mt = 0; mt < 8; mt++) {
        int c = mt * 16 + n;
        vfA[mt] = *(const uint2*)(vtb + (size_t)((wid) * 128 + c) * 16 + q4 * 4);
        vfB[mt] = *(const uint2*)(vtb + (size_t)((wid + 4) * 128 + c) * 16 + q4 * 4);
    }
    f32x4 sA[4], sB[4];
#pragma unroll
    for (int ws = 0; ws < 4; ws++) {
        sA[ws] = __builtin_amdgcn_mfma_f32_16x16x32_bf16(aqA, bk[ws], zero, 0, 0, 0);
        sB[ws] = __builtin_amdgcn_mfma_f32_16x16x32_bf16(aqB, bk[ws], zero, 0, 0, 0);
    }
    aqA = qbase[128 + wid * 16 + n];          // q frags for it=1
    aqB = qbase[128 + 64 + wid * 16 + n];
    bf16x8 bfrag[4];
#pragma unroll
    for (int ws = 0; ws < 4; ws++) bfrag[ws] = exp2pack(sA[ws], sB[ws]);

    for (int it = 0; it < 32; it++) {
        int itn = (it + 1) & 31;
        // (a) v-fragment prefetch for it+1
        uint2 vfA_n[8], vfB_n[8];
        int jtA_n = itn * 8 + wid, jtB_n = jtA_n + 4;
#pragma unroll
        for (int mt = 0; mt < 8; mt++) {
            int c = mt * 16 + n;
            vfA_n[mt] = *(const uint2*)(vtb + (size_t)(jtA_n * 128 + c) * 16 + q4 * 4);
            vfB_n[mt] = *(const uint2*)(vtb + (size_t)(jtB_n * 128 + c) * 16 + q4 * 4);
        }
        // (b) S-MFMAs for it+1 (aq regs hold it+1 frags)
#pragma unroll
        for (int ws = 0; ws < 4; ws++) {
            sA[ws] = __builtin_amdgcn_mfma_f32_16x16x32_bf16(aqA, bk[ws], zero, 0, 0, 0);
            sB[ws] = __builtin_amdgcn_mfma_f32_16x16x32_bf16(aqB, bk[ws], zero, 0, 0, 0);
        }
        // (c) q loads for it+2
        int itn2 = (it + 2) & 31;
        aqA = qbase[itn2 * 128 + wid * 16 + n];
        aqB = qbase[itn2 * 128 + 64 + wid * 16 + n];
        // (d) PV for it (consumes bfrag + vf regs)
#pragma unroll
        for (int mt = 0; mt < 8; mt++) {
            bf16x8 af = u4_to_bf8(vfA[mt].x, vfA[mt].y, vfB[mt].x, vfB[mt].y);
#pragma unroll
            for (int nt = 0; nt < 4; nt++)
                acc[mt][nt] = __builtin_amdgcn_mfma_f32_16x16x32_bf16(af, bfrag[nt], acc[mt][nt], 0, 0, 0);
        }
        // (e) exp2/pack for it+1 -> next bfrag
#pragma unroll
        for (int ws = 0; ws < 4; ws++) bfrag[ws] = exp2pack(sA[ws], sB[ws]);
        // rotate v-frag registers
#pragma unroll
        for (int mt = 0; mt < 8; mt++) { vfA[mt] = vfA_n[mt]; vfB[mt] = vfB_n[mt]; }
    }

    // ---- cross-wave reduction ----
    if (wid >= 2) {
        float* buf = red[wid - 2];
#pragma unroll
        for (int mt = 0; mt < 8; mt++)
#pragma unroll
            for (int nt = 0; nt < 4; nt++)
#pragma unroll
                for (int r = 0; r < 4; r++)
                    buf[(mt * 16 + q4 * 4 + r) * 68 + nt * 16 + n] = acc[mt][nt][r];
    }
    __syncthreads();
    if (wid < 2) {
        const float* buf = red[wid];
#pragma unroll
        for (int mt = 0; mt < 8; mt++)
#pragma unroll
            for (int nt = 0; nt < 4; nt++)
#pragma unroll
                for (int r = 0; r < 4; r++)
                    acc[mt][nt][r] += buf[(mt * 16 + q4 * 4 + r) * 68 + nt * 16 + n];
    }
    __syncthreads();
    if (wid == 1) {
        float* buf = red[0];
#pragma unroll
        for (int mt = 0; mt < 8; mt++)
#pragma unroll
            for (int nt = 0; nt < 4; nt++)
#pragma unroll
                for (int r = 0; r < 4; r++)
                    buf[(mt * 16 + q4 * 4 + r) * 68 + nt * 16 + n] = acc[mt][nt][r];
    }
    __syncthreads();
    if (wid == 0) {
        float* buf = red[0];
#pragma unroll
        for (int mt = 0; mt < 8; mt++)
#pragma unroll
            for (int nt = 0; nt < 4; nt++)
#pragma unroll
                for (int r = 0; r < 4; r++) {
                    int idx = (mt * 16 + q4 * 4 + r) * 68 + nt * 16 + n;
                    buf[idx] = acc[mt][nt][r] + buf[idx];
                }
    }
    __syncthreads();
    // coalesced store: out = red[0] + x
    {
#pragma unroll
        for (int u = 0; u < 8; u++) {
            int k = tid + 256 * u;          // 2048 float4 slots
            int c = k >> 4, wseg = (k & 15) * 4;
            size_t gidx = (size_t)(b * C_ + c) * W_ + w0 + wseg;
            float4 xv = *(const float4*)(x + gidx);
            const float* s = &red[0][c * 68 + wseg];
            float4 o = make_float4(s[0] + xv.x, s[1] + xv.y, s[2] + xv.z, s[3] + xv.w);
            *(float4*)(out + gidx) = o;
        }
    }
}

extern "C" void kernel_launch(void* const* d_in, const int* in_sizes, int n_in,
                              void* d_out, int out_size, void* d_ws, size_t ws_size,
                              hipStream_t stream)
{
    const float* x  = (const float*)d_in[0];
    const float* Wq = (const float*)d_in[1];
    const float* bq = (const float*)d_in[2];
    const float* Wk = (const float*)d_in[3];
    const float* bk = (const float*)d_in[4];
    const float* Wv = (const float*)d_in[5];
    const float* bv = (const float*)d_in[6];
    float* out = (float*)d_out;

    unsigned short* qws  = (unsigned short*)d_ws;        // [B][4][W][8] bf16 = 2MB
    unsigned short* kws  = qws + (size_t)1048576;        // [B][4][W][8] bf16 = 2MB
    unsigned short* vws  = kws + (size_t)1048576;        // [B][W/16][C][16] bf16 = 8MB
    unsigned short* Wvbf = vws + (size_t)4194304;        // [128][128]
    unsigned short* Wqkbf = Wvbf + 16384;                // [32][128] (q rows pre-scaled)
    float* rlp = (float*)(Wqkbf + 4096);                 // [4][B][W] partial l-sums

    prep<<<20, 256, 0, stream>>>(Wq, Wk, Wv, Wvbf, Wqkbf);
    proj<<<1024, 256, 0, stream>>>(x, Wvbf, Wqkbf, bq, bk, bv, qws, kws, vws);
    row_stats<<<2048, 256, 0, stream>>>(qws, kws, rlp);
    finl<<<128, 256, 0, stream>>>(rlp, qws);
    attn_out<<<512, 256, 0, stream>>>(x, qws, kws, vws, out);
}

// Round 9
// 162.447 us; speedup vs baseline: 2.1209x; 1.0014x over previous
//
#include <hip/hip_runtime.h>

#define B_ 8
#define C_ 128
#define W_ 4096
#define D_ 16
// D^-0.5 * log2(e): folded into Wq/bq; exp2 domain (v_exp_f32)
#define SCALE2 0.3606737602222409f

typedef short bf16x8 __attribute__((ext_vector_type(8)));
typedef float f32x4 __attribute__((ext_vector_type(4)));
typedef float f32x16 __attribute__((ext_vector_type(16)));

__device__ __forceinline__ unsigned short f2bf(float f) {
    unsigned int u = __float_as_uint(f);
    u += 0x7fffu + ((u >> 16) & 1u);
    return (unsigned short)(u >> 16);
}
__device__ __forceinline__ float bf2f(unsigned short h) {
    return __uint_as_float(((unsigned int)h) << 16);
}
// pack two f32 -> u32 of 2 bf16 (TRUNCATED) in ONE v_perm_b32
__device__ __forceinline__ unsigned int pk2bf(float lo, float hi) {
    return __builtin_amdgcn_perm(__float_as_uint(hi), __float_as_uint(lo), 0x07060302u);
}
__device__ __forceinline__ bf16x8 u4_to_bf8(unsigned int a, unsigned int b,
                                            unsigned int c, unsigned int d) {
    union { uint4 u; bf16x8 v; } t;
    t.u = make_uint4(a, b, c, d);
    return t.v;
}
__device__ __forceinline__ bf16x8 uint4_as_bf8(uint4 u) {
    union { uint4 u; bf16x8 v; } t;
    t.u = u;
    return t.v;
}
// exp2 8 S-values (C-regs r0..r0+7) -> one K=16 B-fragment (slot i = reg r0+i)
__device__ __forceinline__ bf16x8 exp2pack8(f32x16 s, int r0) {
    return u4_to_bf8(
        pk2bf(__builtin_amdgcn_exp2f(s[r0+0]), __builtin_amdgcn_exp2f(s[r0+1])),
        pk2bf(__builtin_amdgcn_exp2f(s[r0+2]), __builtin_amdgcn_exp2f(s[r0+3])),
        pk2bf(__builtin_amdgcn_exp2f(s[r0+4]), __builtin_amdgcn_exp2f(s[r0+5])),
        pk2bf(__builtin_amdgcn_exp2f(s[r0+6]), __builtin_amdgcn_exp2f(s[r0+7])));
}
// LDS chunk swizzle for proj staging
__device__ __forceinline__ int xswz(int j, int c8) {
    return c8 ^ (j & 7) ^ ((j >> 3) & 7);
}

// ---------------- prep: Wv -> bf16; [Wq*SCALE2 ; Wk] -> bf16 ----------------
__global__ __launch_bounds__(256) void prep(
    const float* __restrict__ Wq, const float* __restrict__ Wk, const float* __restrict__ Wv,
    unsigned short* __restrict__ Wvbf, unsigned short* __restrict__ Wqkbf)
{
    int g = blockIdx.x * 256 + threadIdx.x;
    const float* src; unsigned short* dst; float sc = 1.0f;
    if (g < 4096)      { src = Wv + g * 4;            dst = Wvbf + g * 4; }
    else if (g < 4608) { int t = g - 4096; src = Wq + t * 4; dst = Wqkbf + t * 4; sc = SCALE2; }
    else               { int t = g - 4608; src = Wk + t * 4; dst = Wqkbf + 2048 + t * 4; }
    float4 v = *(const float4*)src;
    unsigned short h[4] = {f2bf(v.x * sc), f2bf(v.y * sc), f2bf(v.z * sc), f2bf(v.w * sc)};
    *(ushort4*)dst = *(ushort4*)h;
}

// ---------------- proj: q,k,v in one pass; frag-major outputs ----------------
// qws2/kws2: [b][pos/32][h 0-1][pos%32][8 dims]  (dims h*8+i; K=16, no padding)
// vws2:      [b][jt][kf 0-1][h 0-1][c 128][8]    slot i -> j = jt*32 + kf*16+4h+(i&3)+8*(i>>2)
__global__ __launch_bounds__(256) void proj(
    const float* __restrict__ x, const unsigned short* __restrict__ Wvbf,
    const unsigned short* __restrict__ Wqkbf,
    const float* __restrict__ bqp, const float* __restrict__ bkp, const float* __restrict__ bvp,
    unsigned short* __restrict__ qws2, unsigned short* __restrict__ kws2,
    unsigned short* __restrict__ vws2)
{
    __shared__ unsigned short xbf[32 * 128];     // [j][c] swizzled chunks, 8KB
    __shared__ unsigned short outs[128 * 36];    // v bounce [c][j], 9KB
    __shared__ unsigned short qk_s[2][32][24];   // q/k bounce [qk][pos][dim], 3KB (row 48B)

    int b  = blockIdx.x & 7;
    int j0 = (blockIdx.x >> 3) * 32;
    int jt = j0 >> 5;
    int tid = threadIdx.x;
    int wid = tid >> 6, lane = tid & 63, n = lane & 15, q4 = lane >> 4;

    // stage x tile [128c][32j] -> bf16 LDS [j][c] swizzled; c-paired v_perm packs
    {
        unsigned int* xbf32 = (unsigned int*)xbf;
#pragma unroll
        for (int i = 0; i < 8; i++) {
            int p = tid + 256 * i;            // 2048 c-pair slots
            int c2 = p >> 5;                  // c = 2*c2, 2*c2+1
            int j  = p & 31;
            const float* xp = x + (size_t)(b * C_ + 2 * c2) * W_ + j0 + j;
            float lo = xp[0];
            float hi = xp[W_];
            xbf32[j * 64 + xswz(j, c2 >> 2) * 4 + (c2 & 3)] = pk2bf(lo, hi);
        }
    }
    __syncthreads();

    const f32x4 zero = {0.f, 0.f, 0.f, 0.f};
    f32x4 accv[2][2]; f32x4 accqk = zero;
#pragma unroll
    for (int os = 0; os < 2; os++)
#pragma unroll
        for (int js = 0; js < 2; js++) accv[os][js] = zero;

    int isK = wid >> 1;          // waves 0,1: q; waves 2,3: k
    int jsm = wid & 1;           // which j-tile this wave's q/k MFMA covers

#pragma unroll
    for (int kk = 0; kk < 128; kk += 32) {
        bf16x8 av[2], aqkf, bx[2];
#pragma unroll
        for (int os = 0; os < 2; os++)
            av[os] = *(const bf16x8*)(Wvbf + (wid * 32 + os * 16 + n) * 128 + kk + q4 * 8);
        aqkf = *(const bf16x8*)(Wqkbf + (isK * 16 + n) * 128 + kk + q4 * 8);
#pragma unroll
        for (int js = 0; js < 2; js++) {
            int j = js * 16 + n;
            bx[js] = *(const bf16x8*)&xbf[j * 128 + xswz(j, (kk >> 3) + q4) * 8];
        }
#pragma unroll
        for (int os = 0; os < 2; os++)
#pragma unroll
            for (int js = 0; js < 2; js++)
                accv[os][js] = __builtin_amdgcn_mfma_f32_16x16x32_bf16(av[os], bx[js], accv[os][js], 0, 0, 0);
        accqk = __builtin_amdgcn_mfma_f32_16x16x32_bf16(aqkf, bx[jsm], accqk, 0, 0, 0);
    }

    // q/k epilogue -> qk_s (C layout: row d = q4*4+r, col pos = jsm*16+n)
    {
        int pos = jsm * 16 + n;
        const float* bias = isK ? bkp : bqp;
        float bsc = isK ? 1.0f : SCALE2;
#pragma unroll
        for (int r = 0; r < 4; r++)
            qk_s[isK][pos][q4 * 4 + r] = f2bf(accqk[r] + bias[q4 * 4 + r] * bsc);
    }

    // v epilogue -> outs [c][j]
    float bvv[2][4];
#pragma unroll
    for (int os = 0; os < 2; os++)
#pragma unroll
        for (int r = 0; r < 4; r++) bvv[os][r] = bvp[wid * 32 + os * 16 + q4 * 4 + r];
#pragma unroll
    for (int os = 0; os < 2; os++)
#pragma unroll
        for (int js = 0; js < 2; js++)
#pragma unroll
            for (int r = 0; r < 4; r++) {
                int c = wid * 32 + os * 16 + q4 * 4 + r;
                int j = js * 16 + n;
                outs[c * 36 + j] = f2bf(accv[os][js][r] + bvv[os][r]);
            }
    __syncthreads();

    // qws2/kws2 writers (128 tasks x 16B)
    if (tid < 128) {
        int qk = tid >> 6, hh = (tid >> 5) & 1, jl = tid & 31;
        uint4 v = *(const uint4*)&qk_s[qk][jl][hh * 8];
        unsigned short* dst = (qk ? kws2 : qws2)
            + (size_t)(b * 128 + jt) * 512 + hh * 256 + jl * 8;
        *(uint4*)dst = v;
    }
    // vws2 writers (512 tasks x 16B): slot i -> j = kf*16+4h+{0..3,8..11}
#pragma unroll
    for (int rep = 0; rep < 2; rep++) {
        int t = tid + rep * 256;
        int c = t & 127, sel = t >> 7;          // sel = kf*2+h
        int jb = (sel >> 1) * 16 + (sel & 1) * 4;
        uint2 lo = *(const uint2*)&outs[c * 36 + jb];
        uint2 hi = *(const uint2*)&outs[c * 36 + jb + 8];
        *(uint4*)(vws2 + ((size_t)(b * 128 + jt) * 4 + sel) * 1024 + c * 8) =
            make_uint4(lo.x, lo.y, hi.x, hi.y);
    }
}

// ---------------- row_stats: partial l-sums via 32x32x16, w split 4 ways ----------------
// rlp[wsp][b][W] = sum over w-quarter of exp2(s2[j,w])
__global__ __launch_bounds__(256) void row_stats(
    const unsigned short* __restrict__ qws2, const unsigned short* __restrict__ kws2,
    float* __restrict__ rlp)
{
    int blk = blockIdx.x;                // grid 1024
    int b = blk & 7;
    int j0 = ((blk >> 3) & 31) * 128;
    int wsp = blk >> 8;                  // 0..3
    int tid = threadIdx.x;
    int wid = tid >> 6, lane = tid & 63, wl = lane & 31, h = lane >> 5;

    const unsigned short* qb = qws2 + (size_t)b * 65536;
    const unsigned short* kb = kws2 + (size_t)b * 65536;
    int jt = (j0 >> 5) + wid;

    bf16x8 aq = *(const bf16x8*)(qb + (size_t)jt * 512 + h * 256 + wl * 8);
    f32x16 zero16 = {0.f,0.f,0.f,0.f,0.f,0.f,0.f,0.f,0.f,0.f,0.f,0.f,0.f,0.f,0.f,0.f};

    float lt[16];
#pragma unroll
    for (int r = 0; r < 16; r++) lt[r] = 0.f;

    bf16x8 bkc = *(const bf16x8*)(kb + (size_t)(wsp * 32) * 512 + h * 256 + wl * 8);
    for (int t = 0; t < 32; t++) {
        f32x16 s = __builtin_amdgcn_mfma_f32_32x32x16_bf16(aq, bkc, zero16, 0, 0, 0);
        int tn = wsp * 32 + ((t + 1) & 31);   // branchless wrap prefetch
        bkc = *(const bf16x8*)(kb + (size_t)tn * 512 + h * 256 + wl * 8);
#pragma unroll
        for (int r = 0; r < 16; r++) lt[r] += __builtin_amdgcn_exp2f(s[r]);
    }
    // reduce over 32 w-lanes (same half)
#pragma unroll
    for (int mask = 1; mask < 32; mask <<= 1)
#pragma unroll
        for (int r = 0; r < 16; r++) lt[r] += __shfl_xor(lt[r], mask, 64);
    if (wl == 0) {
        // C rows: r=4g+e -> j-local = e + 8g + 4h
#pragma unroll
        for (int g = 0; g < 4; g++) {
            f32x4 v = {lt[4*g+0], lt[4*g+1], lt[4*g+2], lt[4*g+3]};
            *(f32x4*)(rlp + (size_t)wsp * 32768 + (size_t)b * W_ + j0 + wid * 32 + 4 * h + 8 * g) = v;
        }
    }
}

// ---------------- finl: rls[j] = 1 / sum of 4 partials ----------------
__global__ __launch_bounds__(256) void finl(const float* __restrict__ rlp,
                                            float* __restrict__ rls)
{
    int g = blockIdx.x * 256 + threadIdx.x;   // 32768 = B*W
    float l = rlp[g] + rlp[32768 + g] + rlp[65536 + g] + rlp[98304 + g];
    rls[g] = 1.0f / l;
}

// ---------------- vscale: v'[c,j] = v[c,j] * rls[j], in-place on vws2 ----------------
__global__ __launch_bounds__(256) void vscale(unsigned short* __restrict__ vws2,
                                              const float* __restrict__ rls)
{
    int g = blockIdx.x * 256 + threadIdx.x;   // 524288 16B-units
    int hh = (g >> 7) & 1, kf = (g >> 8) & 1, jt = (g >> 9) & 127, b = g >> 16;
    int jb = jt * 32 + kf * 16 + 4 * hh;
    const float* rp = rls + (size_t)b * W_ + jb;
    float4 r0 = *(const float4*)rp;          // j jb..jb+3  (slots 0-3)
    float4 r1 = *(const float4*)(rp + 8);    // j jb+8..+11 (slots 4-7)
    uint4 v = *(const uint4*)(vws2 + (size_t)g * 8);
    unsigned int o0 = pk2bf(bf2f((unsigned short)(v.x & 0xffffu)) * r0.x,
                            bf2f((unsigned short)(v.x >> 16))     * r0.y);
    unsigned int o1 = pk2bf(bf2f((unsigned short)(v.y & 0xffffu)) * r0.z,
                            bf2f((unsigned short)(v.y >> 16))     * r0.w);
    unsigned int o2 = pk2bf(bf2f((unsigned short)(v.z & 0xffffu)) * r1.x,
                            bf2f((unsigned short)(v.z >> 16))     * r1.y);
    unsigned int o3 = pk2bf(bf2f((unsigned short)(v.w & 0xffffu)) * r1.z,
                            bf2f((unsigned short)(v.w >> 16))     * r1.w);
    *(uint4*)(vws2 + (size_t)g * 8) = make_uint4(o0, o1, o2, o3);
}

// ---------------- attn_out: 32x32x16 S->exp2->PV, barrier-free pipelined K-loop ----------------
// Wave owns j-tile jt = it*4+wid (32 j per iter). S C-layout feeds PV B in-lane;
// v A-frags (one dwordx4 each) from sigma-arranged vws2. 1/l pre-folded into v.
__global__ __launch_bounds__(256, 2) void attn_out(
    const float* __restrict__ x, const unsigned short* __restrict__ qws2,
    const unsigned short* __restrict__ kws2, const unsigned short* __restrict__ vws2,
    float* __restrict__ out)
{
    __shared__ float red[2][128 * 68];   // 69.6 KB

    int b  = blockIdx.x & 7;
    int w0 = (blockIdx.x >> 3) * 64;
    int tid = threadIdx.x;
    int wid = tid >> 6, lane = tid & 63, wl = lane & 31, h = lane >> 5;

    const unsigned short* qb  = qws2 + (size_t)b * 65536;
    const unsigned short* kb  = kws2 + (size_t)b * 65536;
    const unsigned short* vtb = vws2 + (size_t)b * 524288;

    // loop-invariant k fragments (B of S): 2 w-subtiles
    bf16x8 bk0 = *(const bf16x8*)(kb + (size_t)((w0 >> 5) + 0) * 512 + h * 256 + wl * 8);
    bf16x8 bk1 = *(const bf16x8*)(kb + (size_t)((w0 >> 5) + 1) * 512 + h * 256 + wl * 8);

    f32x16 zero16 = {0.f,0.f,0.f,0.f,0.f,0.f,0.f,0.f,0.f,0.f,0.f,0.f,0.f,0.f,0.f,0.f};
    f32x16 acc[4][2];
#pragma unroll
    for (int mt = 0; mt < 4; mt++)
#pragma unroll
        for (int nt = 0; nt < 2; nt++) acc[mt][nt] = zero16;

    // per-lane base offsets
    const int qoff = h * 256 + wl * 8;
    // vf offset for (mt, kf): kf*2048 + h*1024 + (mt*32+wl)*8

    // ---- prologue: vf(0), s(0), aq(1), bfrag(0) ----
    bf16x8 aq = *(const bf16x8*)(qb + (size_t)(wid) * 512 + qoff);
    uint4 vf[4][2];
#pragma unroll
    for (int mt = 0; mt < 4; mt++)
#pragma unroll
        for (int kf = 0; kf < 2; kf++)
            vf[mt][kf] = *(const uint4*)(vtb + (size_t)wid * 4096 + kf * 2048 + h * 1024 + (mt * 32 + wl) * 8);
    f32x16 s0 = __builtin_amdgcn_mfma_f32_32x32x16_bf16(aq, bk0, zero16, 0, 0, 0);
    f32x16 s1 = __builtin_amdgcn_mfma_f32_32x32x16_bf16(aq, bk1, zero16, 0, 0, 0);
    aq = *(const bf16x8*)(qb + (size_t)(4 + wid) * 512 + qoff);
    bf16x8 bfrag[2][2];                 // [kf][nt]
    bfrag[0][0] = exp2pack8(s0, 0); bfrag[1][0] = exp2pack8(s0, 8);
    bfrag[0][1] = exp2pack8(s1, 0); bfrag[1][1] = exp2pack8(s1, 8);

    for (int it = 0; it < 32; it++) {
        // (a) v-fragment prefetch for it+1
        int jtn = ((it + 1) & 31) * 4 + wid;
        uint4 vfn[4][2];
#pragma unroll
        for (int mt = 0; mt < 4; mt++)
#pragma unroll
            for (int kf = 0; kf < 2; kf++)
                vfn[mt][kf] = *(const uint4*)(vtb + (size_t)jtn * 4096 + kf * 2048 + h * 1024 + (mt * 32 + wl) * 8);
        // (b) PV for it
#pragma unroll
        for (int mt = 0; mt < 4; mt++)
#pragma unroll
            for (int kf = 0; kf < 2; kf++) {
                bf16x8 af = uint4_as_bf8(vf[mt][kf]);
#pragma unroll
                for (int nt = 0; nt < 2; nt++)
                    acc[mt][nt] = __builtin_amdgcn_mfma_f32_32x32x16_bf16(af, bfrag[kf][nt], acc[mt][nt], 0, 0, 0);
            }
        // (c) S for it+1 (aq holds it+1 frag)
        s0 = __builtin_amdgcn_mfma_f32_32x32x16_bf16(aq, bk0, zero16, 0, 0, 0);
        s1 = __builtin_amdgcn_mfma_f32_32x32x16_bf16(aq, bk1, zero16, 0, 0, 0);
        // (d) q load for it+2
        aq = *(const bf16x8*)(qb + (size_t)(((it + 2) & 31) * 4 + wid) * 512 + qoff);
        // (e) exp2/pack -> bfrag(it+1)
        bfrag[0][0] = exp2pack8(s0, 0); bfrag[1][0] = exp2pack8(s0, 8);
        bfrag[0][1] = exp2pack8(s1, 0); bfrag[1][1] = exp2pack8(s1, 8);
        // (f) rotate vf
#pragma unroll
        for (int mt = 0; mt < 4; mt++)
#pragma unroll
            for (int kf = 0; kf < 2; kf++) vf[mt][kf] = vfn[mt][kf];
    }

    // ---- cross-wave reduction (4 waves, j-split) ----
    // acc C layout: row c = mt*32 + (r&3)+8*(r>>2)+4h, col w = nt*32 + wl
#define WRITE_TILE(BUF)                                                           \
    {                                                                             \
        float* _b = (BUF);                                                        \
        _Pragma("unroll") for (int mt = 0; mt < 4; mt++)                          \
        _Pragma("unroll") for (int nt = 0; nt < 2; nt++)                          \
        _Pragma("unroll") for (int r = 0; r < 16; r++)                            \
            _b[(mt * 32 + (r & 3) + 8 * (r >> 2) + 4 * h) * 68 + nt * 32 + wl] = acc[mt][nt][r]; \
    }
#define ADD_TILE(BUF)                                                             \
    {                                                                             \
        const float* _b = (BUF);                                                  \
        _Pragma("unroll") for (int mt = 0; mt < 4; mt++)                          \
        _Pragma("unroll") for (int nt = 0; nt < 2; nt++)                          \
        _Pragma("unroll") for (int r = 0; r < 16; r++)                            \
            acc[mt][nt][r] += _b[(mt * 32 + (r & 3) + 8 * (r >> 2) + 4 * h) * 68 + nt * 32 + wl]; \
    }
    if (wid >= 2) WRITE_TILE(red[wid - 2]);
    __syncthreads();
    if (wid < 2) ADD_TILE(red[wid]);
    __syncthreads();
    if (wid == 1) WRITE_TILE(red[0]);
    __syncthreads();
    if (wid == 0) { ADD_TILE(red[0]); WRITE_TILE(red[0]); }
    __syncthreads();
#undef WRITE_TILE
#undef ADD_TILE

    // coalesced store: out = red[0] + x
#pragma unroll
    for (int u = 0; u < 8; u++) {
        int k = tid + 256 * u;          // 2048 float4 slots
        int c = k >> 4, wseg = (k & 15) * 4;
        size_t gidx = (size_t)(b * C_ + c) * W_ + w0 + wseg;
        float4 xv = *(const float4*)(x + gidx);
        const float* s = &red[0][c * 68 + wseg];
        float4 o = make_float4(s[0] + xv.x, s[1] + xv.y, s[2] + xv.z, s[3] + xv.w);
        *(float4*)(out + gidx) = o;
    }
}

extern "C" void kernel_launch(void* const* d_in, const int* in_sizes, int n_in,
                              void* d_out, int out_size, void* d_ws, size_t ws_size,
                              hipStream_t stream)
{
    const float* x  = (const float*)d_in[0];
    const float* Wq = (const float*)d_in[1];
    const float* bq = (const float*)d_in[2];
    const float* Wk = (const float*)d_in[3];
    const float* bk = (const float*)d_in[4];
    const float* Wv = (const float*)d_in[5];
    const float* bv = (const float*)d_in[6];
    float* out = (float*)d_out;

    unsigned short* qws2 = (unsigned short*)d_ws;        // [B][128][2][32][8] = 1MB
    unsigned short* kws2 = qws2 + (size_t)524288;        // 1MB
    unsigned short* vws2 = kws2 + (size_t)524288;        // [B][128][2][2][128][8] = 8.4MB
    unsigned short* Wvbf = vws2 + (size_t)4194304;       // [128][128]
    unsigned short* Wqkbf = Wvbf + 16384;                // [32][128]
    float* rlp = (float*)(Wqkbf + 4096);                 // [4][B][W] partial l-sums
    float* rls = rlp + 131072;                           // [B][W] reciprocal l

    prep<<<20, 256, 0, stream>>>(Wq, Wk, Wv, Wvbf, Wqkbf);
    proj<<<1024, 256, 0, stream>>>(x, Wvbf, Wqkbf, bq, bk, bv, qws2, kws2, vws2);
    row_stats<<<1024, 256, 0, stream>>>(qws2, kws2, rlp);
    finl<<<128, 256, 0, stream>>>(rlp, rls);
    vscale<<<2048, 256, 0, stream>>>(vws2, rls);
    attn_out<<<512, 256, 0, stream>>>(x, qws2, kws2, vws2, out);
}